// Round 10
// baseline (596.774 us; speedup 1.0000x reference)
//
#include <hip/hip_runtime.h>
#include <hip/hip_cooperative_groups.h>
#include <cstdint>
#include <cstddef>

namespace cg = cooperative_groups;

#define BATCH 8192
#define DIN   1025
#define HID   1024
#define NACT  1026
#define NHEAD 513
#define KSEL  32
#define KP0   1088   /* DIN padded to multiple of 64 */
#define LGN   1024   /* logits cols 0..1023 via GEMM; 1024/1025 computed in sample */
#define GRID  256    /* 256 blocks x 512 threads; coop capacity-safe (>=1 block/CU) */

typedef unsigned short u16;
typedef short bf16x8 __attribute__((ext_vector_type(8)));
typedef float f32x4 __attribute__((ext_vector_type(4)));

__device__ __forceinline__ u16 f2bf(float f) {
  unsigned u = __float_as_uint(f);
  u += 0x7fff + ((u >> 16) & 1);   // round-to-nearest-even
  return (u16)(u >> 16);
}
__device__ __forceinline__ float bf2f(u16 h) {
  return __uint_as_float((unsigned)h << 16);
}

__device__ __forceinline__ void async_cp16(const u16* g, u16* l) {
  __builtin_amdgcn_global_load_lds((const __attribute__((address_space(1))) void*)g,
                                   (__attribute__((address_space(3))) void*)l,
                                   16, 0, 0);
}

struct MegaArgs {
  const float *state, *W0, *b0, *W1, *b1, *W2, *b2;
  const int *idxR, *lenR, *idxS, *lenS;
  u16 *As, *W0t, *W1t, *W2t, *W2c, *h1, *h2, *lgts;
  float *out;
};

// ---------------- phase 0: conversions (512 threads/block) ----------------
__device__ void cvt_phase(const MegaArgs& a, u16* lds) {
  const int tid = threadIdx.x;
  // state f32 [B][DIN] -> bf16 [B][KP0], 4 elems per task, grid-stride
  const int QPR = KP0 / 4;   // 272
  for (int i = blockIdx.x * 512 + tid; i < BATCH * QPR; i += GRID * 512) {
    int r = i / QPR, c4 = (i - r * QPR) * 4;
    const float* src = a.state + (size_t)r * DIN + c4;
    ushort4 o;
    if (c4 + 3 < DIN) {
      o.x = f2bf(src[0]); o.y = f2bf(src[1]); o.z = f2bf(src[2]); o.w = f2bf(src[3]);
    } else {
      o.x = (c4 + 0 < DIN) ? f2bf(src[0]) : 0;
      o.y = (c4 + 1 < DIN) ? f2bf(src[1]) : 0;
      o.z = (c4 + 2 < DIN) ? f2bf(src[2]) : 0;
      o.w = (c4 + 3 < DIN) ? f2bf(src[3]) : 0;
    }
    *(ushort4*)(a.As + (size_t)r * KP0 + c4) = o;
  }
  // weights -> transposed bf16 in 32x32 tiles: W0t 1088 tiles, W1t 1024, W2t 1024, +W2c
  float (*tile)[33] = (float(*)[33])lds;
  const int tx = tid & 31, ty = tid >> 5;   // ty 0..15
  for (int t = blockIdx.x; t < 3137; t += GRID) {
    if (t == 3136) {   // W2 cols 1024,1025 -> W2c[2][1024] bf16 (block-uniform branch)
      for (int e = tid; e < 2048; e += 512) {
        int j = e >> 10, k = e & 1023;
        a.W2c[e] = f2bf(a.W2[(size_t)k * NACT + 1024 + j]);
      }
      continue;
    }
    const float* W; u16* Wt; int K, ldW, Kp, tt = t;
    if (tt < 1088)      { W = a.W0; Wt = a.W0t; K = DIN; ldW = HID;  Kp = KP0; }
    else if (tt < 2112) { tt -= 1088; W = a.W1; Wt = a.W1t; K = HID; ldW = HID;  Kp = HID; }
    else                { tt -= 2112; W = a.W2; Wt = a.W2t; K = HID; ldW = NACT; Kp = HID; }
    int n0 = (tt & 31) * 32, k0 = (tt >> 5) * 32;
#pragma unroll
    for (int i = 0; i < 32; i += 16) {
      int k = k0 + ty + i;
      tile[ty + i][tx] = (k < K) ? W[(size_t)k * ldW + n0 + tx] : 0.f;
    }
    __syncthreads();
#pragma unroll
    for (int i = 0; i < 32; i += 16)
      Wt[(size_t)(n0 + ty + i) * Kp + k0 + tx] = f2bf(tile[tx][ty + i]);
    __syncthreads();
  }
}

// ---- GEMM phase: 2 tile-teams per block (2x4 waves), 512 tiles total -----------
// Team t of block b computes tile (mtile, ntile): mtile = (b>>5)*8 + (b&7),
// ntile = ((b>>3)&3)*2 + t  -> all 8 ntiles of an mtile land on one XCD (b%8).
// Per team: r7 structure — 128x128 tile, BK=32, dbuf 2x16KB private LDS,
// RAW s_barrier + s_waitcnt vmcnt(4) (next-iter staging in flight across barrier).
// s_barrier is block-wide; both teams run identical trip counts so barriers align.
template<bool RELU, int K>
__device__ void gemm_phase(const u16* __restrict__ A, const u16* __restrict__ Bt,
                           const float* __restrict__ bias, u16* __restrict__ Cout,
                           int ldc, u16* lds0)
{
  const int tid  = threadIdx.x;
  const int team = tid >> 8;         // 0/1
  const int ttid = tid & 255;
  const int wave = ttid >> 6;
  const int lane = tid & 63;
  const int waveM = wave >> 1, waveN = wave & 1;
  const int lr = lane & 15, lq = lane >> 4;

  const int b = blockIdx.x;
  const int mtile = ((b >> 5) << 3) | (b & 7);
  const int ntile = (((b >> 3) & 3) << 1) | team;
  const size_t bm = (size_t)mtile * 128;
  const size_t bn = (size_t)ntile * 128;

  u16* lds = lds0 + team * 16384;    // 32 KB per team (2 bufs x 16 KB)

  // staging: 512 chunks/tile of 16B; chunk c -> row c>>2, slot c&3;
  // data = global kchunk g = (c&3) ^ ((row>>1)&3)
  const int c0   = wave * 64 + lane;
  const int row0 = c0 >> 2;
  const int g0   = (c0 & 3) ^ ((row0 >> 1) & 3);
  const int c1   = c0 + 256;
  const int row1 = c1 >> 2;
  const int g1   = (c1 & 3) ^ ((row1 >> 1) & 3);
  const u16* gA0 = A  + (bm + row0) * (size_t)K + g0 * 8;
  const u16* gA1 = A  + (bm + row1) * (size_t)K + g1 * 8;
  const u16* gB0 = Bt + (bn + row0) * (size_t)K + g0 * 8;
  const u16* gB1 = Bt + (bn + row1) * (size_t)K + g1 * 8;
  u16* lA = lds + wave * 512;
  u16* lB = lds + 4096 + wave * 512;

  f32x4 acc[4][4] = {};

  const int s = lq ^ ((lr >> 1) & 3);
  const u16* pa = lds + (waveM * 64 + lr) * 32 + s * 8;
  const u16* pb = lds + 4096 + (waveN * 64 + lr) * 32 + s * 8;

  auto issue = [&](int k0, int buf) {
    u16* aa = lA + buf * 8192;
    u16* bb = lB + buf * 8192;
    async_cp16(gA0 + k0, aa);
    async_cp16(gA1 + k0, aa + 2048);
    async_cp16(gB0 + k0, bb);
    async_cp16(gB1 + k0, bb + 2048);
  };

  const int NIT = K / 32;
  issue(0, 0);
#pragma unroll 2
  for (int it = 0; it < NIT; ++it) {
    const int buf = it & 1;
    if (it + 1 < NIT) {
      issue((it + 1) * 32, buf ^ 1);
      asm volatile("s_waitcnt vmcnt(4)\n\ts_barrier" ::: "memory");
    } else {
      asm volatile("s_waitcnt vmcnt(0)\n\ts_barrier" ::: "memory");
    }

    bf16x8 af[4], bf[4];
    const u16* qa = pa + buf * 8192;
    const u16* qb = pb + buf * 8192;
#pragma unroll
    for (int t = 0; t < 4; ++t) {
      af[t] = *(const bf16x8*)(qa + t * 512);
      bf[t] = *(const bf16x8*)(qb + t * 512);
    }
#pragma unroll
    for (int tm = 0; tm < 4; ++tm)
#pragma unroll
      for (int tn = 0; tn < 4; ++tn)
        acc[tm][tn] = __builtin_amdgcn_mfma_f32_16x16x32_bf16(af[tm], bf[tn], acc[tm][tn], 0, 0, 0);

    asm volatile("s_waitcnt lgkmcnt(0)\n\ts_barrier" ::: "memory");
  }

  // epilogue: D row = lq*4 + r, col = lr (m89-verified layout)
#pragma unroll
  for (int tm = 0; tm < 4; ++tm) {
    size_t rw = bm + waveM * 64 + tm * 16 + lq * 4;
#pragma unroll
    for (int tn = 0; tn < 4; ++tn) {
      int col = (int)bn + waveN * 64 + tn * 16 + lr;
      float bv = bias[col];
#pragma unroll
      for (int r = 0; r < 4; ++r) {
        float v = acc[tm][tn][r] + bv;
        if (RELU) v = fmaxf(v, 0.f);
        Cout[(rw + r) * ldc + col] = f2bf(v);
      }
    }
  }
}

// ---------------- phase 4: sampling without replacement (512 threads) ------------
// 8 waves/block = 4 row-pairs x {R,S}. Group S cols 513..1025: 513..1023 from lgts,
// 1024/1025 computed here from h2 row x W2c (wave-reduced dots).
__device__ void sample_phase(const MegaArgs& a, u16* lds) {
  float* shf = (float*)lds;   // 16 floats
  const int tid = threadIdx.x;
  const int w = tid >> 6, lane = tid & 63;
  const int grp = w & 1, pair = w >> 1;
  for (int it = 0; it < 8; ++it) {
    const int row = it * 1024 + blockIdx.x * 4 + pair;
    const u16* base = a.lgts + (size_t)row * LGN + (grp ? NHEAD : 0);
    const int* sidx = (grp ? a.idxS : a.idxR) + (size_t)row * KSEL;
    const int slen  = (grp ? a.lenS : a.lenR)[row];

    float x1024 = 0.f, x1025 = 0.f;
    if (grp) {
      float d0 = 0.f, d1 = 0.f;
      const u16* hr  = a.h2 + (size_t)row * HID + lane * 16;
      const u16* w0p = a.W2c + lane * 16;
      const u16* w1p = a.W2c + 1024 + lane * 16;
#pragma unroll
      for (int j = 0; j < 16; ++j) {
        float h = bf2f(hr[j]);
        d0 += h * bf2f(w0p[j]);
        d1 += h * bf2f(w1p[j]);
      }
#pragma unroll
      for (int dd = 32; dd; dd >>= 1) { d0 += __shfl_xor(d0, dd, 64); d1 += __shfl_xor(d1, dd, 64); }
      x1024 = d0 + a.b2[1024];
      x1025 = d1 + a.b2[1025];
    }
    const int NHm = grp ? 511 : 513;   // elems from memory; S adds x1024/x1025

    float m = -3.4e38f;
    for (int i = lane; i < NHm; i += 64) m = fmaxf(m, bf2f(base[i]));
    if (grp) {
      if (lane == 63) m = fmaxf(m, x1024);
      if (lane == 0)  m = fmaxf(m, x1025);
    }
#pragma unroll
    for (int dd = 32; dd; dd >>= 1) m = fmaxf(m, __shfl_xor(m, dd, 64));

    float S = 0.f, T = 0.f;
    for (int i = lane; i < NHm; i += 64) {
      float xi = bf2f(base[i]);
      float e = __expf(xi - m);
      S += e; T += e * xi;
    }
    if (grp) {
      if (lane == 63) { float e = __expf(x1024 - m); S += e; T += e * x1024; }
      if (lane == 0)  { float e = __expf(x1025 - m); S += e; T += e * x1025; }
    }
#pragma unroll
    for (int dd = 32; dd; dd >>= 1) { S += __shfl_xor(S, dd, 64); T += __shfl_xor(T, dd, 64); }

    float e = 0.f, ex = 0.f, xt = 0.f;
    int active = (lane < KSEL) && (lane < slen);
    int valid = 0;
    if (active) {
      int id = sidx[lane];
      if (id >= 0) {
        valid = 1;
        if (grp && id >= 511) xt = (id == 511) ? x1024 : x1025;
        else                  xt = bf2f(base[id]);
        e  = __expf(xt - m);
        ex = e * xt;
      }
    }
    float pe = e, pex = ex;
#pragma unroll
    for (int dd = 1; dd < 32; dd <<= 1) {
      float qa = __shfl_up(pe, dd, 64);
      float qb = __shfl_up(pex, dd, 64);
      if (lane >= dd) { pe += qa; pex += qb; }
    }
    float lp = 0.f, en = 0.f;
    if (active) {
      float St = S - (pe - e);
      float Tt = T - (pex - ex);
      float logZ = m + __logf(St);
      en = logZ - Tt / St;
      if (valid) lp = xt - logZ;
    }
#pragma unroll
    for (int dd = 32; dd; dd >>= 1) { lp += __shfl_xor(lp, dd, 64); en += __shfl_xor(en, dd, 64); }

    if (lane == 0) { shf[w * 2] = lp; shf[w * 2 + 1] = en; }
    __syncthreads();
    if (lane == 0 && grp == 0) {
      a.out[row]         = shf[pair * 4] + shf[pair * 4 + 2];
      a.out[BATCH + row] = shf[pair * 4 + 1] + shf[pair * 4 + 3];
    }
    __syncthreads();
  }
}

// ---------------- kernels ----------------
__global__ __launch_bounds__(512, 2) void mega(MegaArgs a) {
  __shared__ __align__(16) u16 lds[32768];   // 64 KB
  cg::grid_group g = cg::this_grid();
  cvt_phase(a, lds);
  __threadfence(); g.sync();
  gemm_phase<true,  KP0>(a.As, a.W0t, a.b0, a.h1, HID, lds);
  __threadfence(); g.sync();
  gemm_phase<true,  HID>(a.h1, a.W1t, a.b1, a.h2, HID, lds);
  __threadfence(); g.sync();
  gemm_phase<false, HID>(a.h2, a.W2t, a.b2, a.lgts, LGN, lds);
  __threadfence(); g.sync();
  sample_phase(a, lds);
}

// fallback wrappers: identical phase code, identical geometry (256 x 512)
__global__ __launch_bounds__(512, 2) void k_cvt(MegaArgs a) {
  __shared__ __align__(16) u16 lds[32768];
  cvt_phase(a, lds);
}
__global__ __launch_bounds__(512, 2) void k_gemm1(MegaArgs a) {
  __shared__ __align__(16) u16 lds[32768];
  gemm_phase<true, KP0>(a.As, a.W0t, a.b0, a.h1, HID, lds);
}
__global__ __launch_bounds__(512, 2) void k_gemm2(MegaArgs a) {
  __shared__ __align__(16) u16 lds[32768];
  gemm_phase<true, HID>(a.h1, a.W1t, a.b1, a.h2, HID, lds);
}
__global__ __launch_bounds__(512, 2) void k_gemm3(MegaArgs a) {
  __shared__ __align__(16) u16 lds[32768];
  gemm_phase<false, HID>(a.h2, a.W2t, a.b2, a.lgts, LGN, lds);
}
__global__ __launch_bounds__(512, 2) void k_sample(MegaArgs a) {
  __shared__ __align__(16) u16 lds[32768];
  sample_phase(a, lds);
}

// ---------------- launch ----------------
extern "C" void kernel_launch(void* const* d_in, const int* in_sizes, int n_in,
                              void* d_out, int out_size, void* d_ws, size_t ws_size,
                              hipStream_t stream) {
  (void)in_sizes; (void)n_in; (void)out_size; (void)ws_size;
  char* ws = (char*)d_ws;
  size_t off = 0;
  auto alloc = [&](size_t bytes) -> char* {
    char* p = ws + off;
    off = (off + bytes + 255) & ~(size_t)255;
    return p;
  };

  MegaArgs a;
  a.state = (const float*)d_in[0];
  a.W0 = (const float*)d_in[1];  a.b0 = (const float*)d_in[2];
  a.W1 = (const float*)d_in[3];  a.b1 = (const float*)d_in[4];
  a.W2 = (const float*)d_in[5];  a.b2 = (const float*)d_in[6];
  a.idxR = (const int*)d_in[7];  a.lenR = (const int*)d_in[8];
  a.idxS = (const int*)d_in[9];  a.lenS = (const int*)d_in[10];
  a.out = (float*)d_out;

  a.As   = (u16*)alloc((size_t)BATCH * KP0 * 2);   // 17.8 MB
  a.W0t  = (u16*)alloc((size_t)HID * KP0 * 2);     //  2.2 MB
  a.W1t  = (u16*)alloc((size_t)HID * HID * 2);     //  2.1 MB
  a.W2t  = (u16*)alloc((size_t)HID * LGN * 2);     //  2.1 MB
  a.W2c  = (u16*)alloc((size_t)2 * 1024 * 2);      //  4 KB
  a.h1   = (u16*)alloc((size_t)BATCH * HID * 2);   // 16.8 MB
  a.h2   = (u16*)alloc((size_t)BATCH * HID * 2);   // 16.8 MB
  a.lgts = (u16*)alloc((size_t)BATCH * LGN * 2);   // 16.8 MB

  void* params[] = { &a };
  hipError_t err = hipLaunchCooperativeKernel((const void*)mega, dim3(GRID), dim3(512),
                                              params, 0, stream);
  if (err != hipSuccess) {
    (void)hipGetLastError();   // clear sticky error so the harness doesn't trip on it
    k_cvt   <<<GRID, 512, 0, stream>>>(a);
    k_gemm1 <<<GRID, 512, 0, stream>>>(a);
    k_gemm2 <<<GRID, 512, 0, stream>>>(a);
    k_gemm3 <<<GRID, 512, 0, stream>>>(a);
    k_sample<<<GRID, 512, 0, stream>>>(a);
  }
}

// Round 11
// 194.373 us; speedup vs baseline: 3.0703x; 3.0703x over previous
//
#include <hip/hip_runtime.h>
#include <cstdint>
#include <cstddef>

#define BATCH 8192
#define DIN   1025
#define HID   1024
#define NACT  1026
#define NHEAD 513
#define KSEL  32
#define KP0   1088   /* DIN padded to multiple of 64 */
#define LGN   1024   /* logits cols 0..1023 via GEMM; 1024/1025 computed in sample */

typedef unsigned short u16;
typedef short bf16x8 __attribute__((ext_vector_type(8)));
typedef float f32x4 __attribute__((ext_vector_type(4)));

__device__ __forceinline__ u16 f2bf(float f) {
  unsigned u = __float_as_uint(f);
  u += 0x7fff + ((u >> 16) & 1);   // round-to-nearest-even
  return (u16)(u >> 16);
}
__device__ __forceinline__ float bf2f(u16 h) {
  return __uint_as_float((unsigned)h << 16);
}

__device__ __forceinline__ void async_cp16(const u16* g, u16* l) {
  __builtin_amdgcn_global_load_lds((const __attribute__((address_space(1))) void*)g,
                                   (__attribute__((address_space(3))) void*)l,
                                   16, 0, 0);
}

// ---------------- conversion kernel (512 thr, grid 4352) ----------------
// blocks: state cvt one pass (4352*512*4 = BATCH*KP0); blocks 0..3136 also do one
// 32x32 weight-transpose tile each (W0t 1088, W1t 1024, W2t 1024, W2c 1).
__global__ __launch_bounds__(512) void k_cvt(const float* __restrict__ state,
    const float* __restrict__ W0, const float* __restrict__ W1,
    const float* __restrict__ W2,
    u16* __restrict__ As, u16* __restrict__ W0t, u16* __restrict__ W1t,
    u16* __restrict__ W2t, u16* __restrict__ W2c) {
  const int tid = threadIdx.x;
  const int b = blockIdx.x;
  // state f32 [B][DIN] -> bf16 [B][KP0], 4 elems/thread
  {
    int i = b * 512 + tid;
    const int QPR = KP0 / 4;   // 272
    int r = i / QPR, c4 = (i - r * QPR) * 4;
    const float* src = state + (size_t)r * DIN + c4;
    ushort4 o;
    if (c4 + 3 < DIN) {
      o.x = f2bf(src[0]); o.y = f2bf(src[1]); o.z = f2bf(src[2]); o.w = f2bf(src[3]);
    } else {
      o.x = (c4 + 0 < DIN) ? f2bf(src[0]) : 0;
      o.y = (c4 + 1 < DIN) ? f2bf(src[1]) : 0;
      o.z = (c4 + 2 < DIN) ? f2bf(src[2]) : 0;
      o.w = (c4 + 3 < DIN) ? f2bf(src[3]) : 0;
    }
    *(ushort4*)(As + (size_t)r * KP0 + c4) = o;
  }
  if (b >= 3137) return;
  if (b == 3136) {   // W2 cols 1024,1025 -> W2c[2][1024]
    for (int e = tid; e < 2048; e += 512) {
      int j = e >> 10, k = e & 1023;
      W2c[e] = f2bf(W2[(size_t)k * NACT + 1024 + j]);
    }
    return;
  }
  const float* W; u16* Wt; int K, ldW, Kp, tt = b;
  if (tt < 1088)      { W = W0; Wt = W0t; K = DIN; ldW = HID;  Kp = KP0; }
  else if (tt < 2112) { tt -= 1088; W = W1; Wt = W1t; K = HID; ldW = HID;  Kp = HID; }
  else                { tt -= 2112; W = W2; Wt = W2t; K = HID; ldW = NACT; Kp = HID; }
  int n0 = (tt & 31) * 32, k0 = (tt >> 5) * 32;
  __shared__ float tile[32][33];
  const int tx = tid & 31, ty = tid >> 5;   // ty 0..15
#pragma unroll
  for (int i = 0; i < 32; i += 16) {
    int k = k0 + ty + i;
    tile[ty + i][tx] = (k < K) ? W[(size_t)k * ldW + n0 + tx] : 0.f;
  }
  __syncthreads();
#pragma unroll
  for (int i = 0; i < 32; i += 16)
    Wt[(size_t)(n0 + ty + i) * Kp + k0 + tx] = f2bf(tile[tx][ty + i]);
}

// ---- high-intensity GEMM: block tile 128x256, 512 thr = 8 waves of 64x64 --------
// C[M][ldc=1024] = A[M][K]*Bt[1024][K]^T (+bias, relu). BK=32; per iter the block
// stages A 8KB + B 16KB (24 KB per 1M MACs = 42.7 MAC/B -> fits the ~1.9 KB/cyc
// per-XCD L2 slice at 256 blocks = 1 block/CU). Dbuf LDS (2x24KB), RAW s_barrier +
// s_waitcnt vmcnt(3): next iter's 3 staging loads stay in flight across the
// barrier. XCD swizzle: d = group*32 + ntile*8 + m8 -> all 4 ntiles of an mtile on
// one XCD (A tile 1 miss + 3 L2 hits; B panel 2.2 MB L2-resident per XCD).
// XOR bank swizzle as r7 (<=2-way ds_read_b128, free).
template<bool RELU, int K>
__global__ __launch_bounds__(512, 2)
void gemm_bt(const u16* __restrict__ A, const u16* __restrict__ Bt,
             const float* __restrict__ bias, u16* __restrict__ Cout, int ldc)
{
  __shared__ __align__(16) u16 lds[24576];   // 2 bufs x (A 4096 + B 8192 u16) = 48 KB

  const int d     = blockIdx.x;
  const int m8    = d & 7;
  const int ntile = (d >> 3) & 3;
  const int mtile = ((d >> 5) << 3) | m8;
  const size_t bm = (size_t)mtile * 128;
  const size_t bn = (size_t)ntile * 256;

  const int tid  = threadIdx.x;
  const int wave = tid >> 6;
  const int lane = tid & 63;
  const int waveM = wave >> 2, waveN = wave & 3;   // 2 x 4 waves
  const int lr = lane & 15, lq = lane >> 4;

  // staging (per thread, 3 chunks of 16B):
  //  A: chunk cA = tid (512 chunks), row = cA>>2, data kchunk g = (cA&3)^((row>>1)&3)
  //  B: chunks tid and tid+512 (1024 chunks), same row/slot rule
  const int rowA  = tid >> 2;
  const int gA_   = (tid & 3) ^ ((rowA >> 1) & 3);
  const int rowB0 = tid >> 2;
  const int gB0_  = (tid & 3) ^ ((rowB0 >> 1) & 3);
  const int rowB1 = rowB0 + 128;
  const int gB1_  = (tid & 3) ^ ((rowB1 >> 1) & 3);
  const u16* gA  = A  + (bm + rowA)  * (size_t)K + gA_  * 8;
  const u16* gB0 = Bt + (bn + rowB0) * (size_t)K + gB0_ * 8;
  const u16* gB1 = Bt + (bn + rowB1) * (size_t)K + gB1_ * 8;
  u16* lA  = lds + wave * 512;          // +buf*12288
  u16* lB0 = lds + 4096 + wave * 512;   // +buf*12288; inst1 at +4096
  u16* lB1 = lB0 + 4096;

  f32x4 acc[4][4] = {};

  // fragment: element (row, lq*8..) at slot s = lq ^ ((lr>>1)&3)
  const int s = lq ^ ((lr >> 1) & 3);
  const u16* pa = lds + (waveM * 64 + lr) * 32 + s * 8;
  const u16* pb = lds + 4096 + (waveN * 64 + lr) * 32 + s * 8;

  auto issue = [&](int k0, int buf) {
    const int o = buf * 12288;
    async_cp16(gA  + k0, lA  + o);
    async_cp16(gB0 + k0, lB0 + o);
    async_cp16(gB1 + k0, lB1 + o);
  };

  const int NIT = K / 32;
  issue(0, 0);
#pragma unroll 2
  for (int it = 0; it < NIT; ++it) {
    const int buf = it & 1;
    if (it + 1 < NIT) {
      issue((it + 1) * 32, buf ^ 1);
      asm volatile("s_waitcnt vmcnt(3)\n\ts_barrier" ::: "memory");
    } else {
      asm volatile("s_waitcnt vmcnt(0)\n\ts_barrier" ::: "memory");
    }

    bf16x8 af[4], bf[4];
    const u16* qa = pa + buf * 12288;
    const u16* qb = pb + buf * 12288;
#pragma unroll
    for (int t = 0; t < 4; ++t) {
      af[t] = *(const bf16x8*)(qa + t * 512);   // +16 rows * 32 stride
      bf[t] = *(const bf16x8*)(qb + t * 512);
    }
#pragma unroll
    for (int tm = 0; tm < 4; ++tm)
#pragma unroll
      for (int tn = 0; tn < 4; ++tn)
        acc[tm][tn] = __builtin_amdgcn_mfma_f32_16x16x32_bf16(af[tm], bf[tn], acc[tm][tn], 0, 0, 0);

    asm volatile("s_waitcnt lgkmcnt(0)\n\ts_barrier" ::: "memory");
  }

  // epilogue: D row = lq*4 + r, col = lr (m89-verified layout)
#pragma unroll
  for (int tm = 0; tm < 4; ++tm) {
    size_t rw = bm + waveM * 64 + tm * 16 + lq * 4;
#pragma unroll
    for (int tn = 0; tn < 4; ++tn) {
      int col = (int)bn + waveN * 64 + tn * 16 + lr;
      float bv = bias[col];
#pragma unroll
      for (int r = 0; r < 4; ++r) {
        float v = acc[tm][tn][r] + bv;
        if (RELU) v = fmaxf(v, 0.f);
        Cout[(rw + r) * ldc + col] = f2bf(v);
      }
    }
  }
}

// ---------------- sampling (512 thr, grid 2048; 4 rows/block) --------------------
// 8 waves = 4 row-pairs x {R,S}. S group cols 513..1025: 513..1023 from lgts,
// 1024/1025 computed from h2 row x W2c (wave-reduced dots). Verified in r10.
__global__ __launch_bounds__(512) void k_sample(const u16* __restrict__ lgts,
    const u16* __restrict__ h2, const u16* __restrict__ W2c,
    const float* __restrict__ b2,
    const int* __restrict__ idxR, const int* __restrict__ lenR,
    const int* __restrict__ idxS, const int* __restrict__ lenS,
    float* __restrict__ out) {
  __shared__ float shf[16];
  const int tid = threadIdx.x;
  const int w = tid >> 6, lane = tid & 63;
  const int grp = w & 1, pair = w >> 1;
  const int row = blockIdx.x * 4 + pair;
  const u16* base = lgts + (size_t)row * LGN + (grp ? NHEAD : 0);
  const int* sidx = (grp ? idxS : idxR) + (size_t)row * KSEL;
  const int slen  = (grp ? lenS : lenR)[row];

  float x1024 = 0.f, x1025 = 0.f;
  if (grp) {
    float d0 = 0.f, d1 = 0.f;
    const u16* hr  = h2 + (size_t)row * HID + lane * 16;
    const u16* w0p = W2c + lane * 16;
    const u16* w1p = W2c + 1024 + lane * 16;
#pragma unroll
    for (int j = 0; j < 16; ++j) {
      float h = bf2f(hr[j]);
      d0 += h * bf2f(w0p[j]);
      d1 += h * bf2f(w1p[j]);
    }
#pragma unroll
    for (int dd = 32; dd; dd >>= 1) { d0 += __shfl_xor(d0, dd, 64); d1 += __shfl_xor(d1, dd, 64); }
    x1024 = d0 + b2[1024];
    x1025 = d1 + b2[1025];
  }
  const int NHm = grp ? 511 : 513;

  float m = -3.4e38f;
  for (int i = lane; i < NHm; i += 64) m = fmaxf(m, bf2f(base[i]));
  if (grp) {
    if (lane == 63) m = fmaxf(m, x1024);
    if (lane == 0)  m = fmaxf(m, x1025);
  }
#pragma unroll
  for (int dd = 32; dd; dd >>= 1) m = fmaxf(m, __shfl_xor(m, dd, 64));

  float S = 0.f, T = 0.f;
  for (int i = lane; i < NHm; i += 64) {
    float xi = bf2f(base[i]);
    float e = __expf(xi - m);
    S += e; T += e * xi;
  }
  if (grp) {
    if (lane == 63) { float e = __expf(x1024 - m); S += e; T += e * x1024; }
    if (lane == 0)  { float e = __expf(x1025 - m); S += e; T += e * x1025; }
  }
#pragma unroll
  for (int dd = 32; dd; dd >>= 1) { S += __shfl_xor(S, dd, 64); T += __shfl_xor(T, dd, 64); }

  float e = 0.f, ex = 0.f, xt = 0.f;
  int active = (lane < KSEL) && (lane < slen);
  int valid = 0;
  if (active) {
    int id = sidx[lane];
    if (id >= 0) {
      valid = 1;
      if (grp && id >= 511) xt = (id == 511) ? x1024 : x1025;
      else                  xt = bf2f(base[id]);
      e  = __expf(xt - m);
      ex = e * xt;
    }
  }
  float pe = e, pex = ex;
#pragma unroll
  for (int dd = 1; dd < 32; dd <<= 1) {
    float qa = __shfl_up(pe, dd, 64);
    float qb = __shfl_up(pex, dd, 64);
    if (lane >= dd) { pe += qa; pex += qb; }
  }
  float lp = 0.f, en = 0.f;
  if (active) {
    float St = S - (pe - e);
    float Tt = T - (pex - ex);
    float logZ = m + __logf(St);
    en = logZ - Tt / St;
    if (valid) lp = xt - logZ;
  }
#pragma unroll
  for (int dd = 32; dd; dd >>= 1) { lp += __shfl_xor(lp, dd, 64); en += __shfl_xor(en, dd, 64); }

  if (lane == 0) { shf[w * 2] = lp; shf[w * 2 + 1] = en; }
  __syncthreads();
  if (lane == 0 && grp == 0) {
    out[row]         = shf[pair * 4] + shf[pair * 4 + 2];
    out[BATCH + row] = shf[pair * 4 + 1] + shf[pair * 4 + 3];
  }
}

// ---------------- launch ----------------
extern "C" void kernel_launch(void* const* d_in, const int* in_sizes, int n_in,
                              void* d_out, int out_size, void* d_ws, size_t ws_size,
                              hipStream_t stream) {
  (void)in_sizes; (void)n_in; (void)out_size; (void)ws_size;
  const float* state = (const float*)d_in[0];
  const float* W0 = (const float*)d_in[1];
  const float* b0 = (const float*)d_in[2];
  const float* W1 = (const float*)d_in[3];
  const float* b1 = (const float*)d_in[4];
  const float* W2 = (const float*)d_in[5];
  const float* b2 = (const float*)d_in[6];
  const int* idxR = (const int*)d_in[7];
  const int* lenR = (const int*)d_in[8];
  const int* idxS = (const int*)d_in[9];
  const int* lenS = (const int*)d_in[10];
  float* out = (float*)d_out;

  char* ws = (char*)d_ws;
  size_t off = 0;
  auto alloc = [&](size_t bytes) -> char* {
    char* p = ws + off;
    off = (off + bytes + 255) & ~(size_t)255;
    return p;
  };
  u16* As   = (u16*)alloc((size_t)BATCH * KP0 * 2);   // 17.8 MB
  u16* W0t  = (u16*)alloc((size_t)HID * KP0 * 2);     //  2.2 MB
  u16* W1t  = (u16*)alloc((size_t)HID * HID * 2);     //  2.1 MB
  u16* W2t  = (u16*)alloc((size_t)HID * LGN * 2);     //  2.1 MB
  u16* W2c  = (u16*)alloc((size_t)2 * 1024 * 2);      //  4 KB
  u16* h1   = (u16*)alloc((size_t)BATCH * HID * 2);   // 16.8 MB
  u16* h2   = (u16*)alloc((size_t)BATCH * HID * 2);   // 16.8 MB
  u16* lgts = (u16*)alloc((size_t)BATCH * LGN * 2);   // 16.8 MB

  k_cvt<<<4352, 512, 0, stream>>>(state, W0, W1, W2, As, W0t, W1t, W2t, W2c);

  gemm_bt<true,  KP0><<<256, 512, 0, stream>>>(As, W0t, b0, h1,   HID);
  gemm_bt<true,  HID><<<256, 512, 0, stream>>>(h1, W1t, b1, h2,   HID);
  gemm_bt<false, HID><<<256, 512, 0, stream>>>(h2, W2t, b2, lgts, LGN);

  k_sample<<<2048, 512, 0, stream>>>(lgts, h2, W2c, b2, idxR, lenR, idxS, lenS, out);
}